// Round 12
// baseline (431.603 us; speedup 1.0000x reference)
//
#include <hip/hip_runtime.h>

typedef unsigned short u16;
typedef unsigned int   u32;

#define Bv  16
#define Nv  512
#define Cv  512
#define NSv 16
#define CCv 64

typedef __attribute__((ext_vector_type(8))) short bf16x8;
typedef __attribute__((ext_vector_type(4))) float f32x4;

__device__ __forceinline__ u16 f2bf(float f) {   // RNE fp32 -> bf16
  u32 b = __float_as_uint(f);
  return (u16)((b + 0x7fffu + ((b >> 16) & 1u)) >> 16);
}
__device__ __forceinline__ u32 pack2(float lo, float hi) {
  return (u32)f2bf(lo) | ((u32)f2bf(hi) << 16);
}

// ---------------- kNN: register-resident compare-exchange top-16 (unchanged, PASS) ----------
__global__ __launch_bounds__(256) void knn_kernel(const float* __restrict__ p,
                                                  int* __restrict__ idx_out) {
#pragma clang fp contract(off)
  __shared__ float4 pnts[Nv];
  __shared__ float  ld[64][65];
  __shared__ int    li[64][65];
  const int b  = blockIdx.y;
  const int q0 = blockIdx.x * 64;
  const int t  = threadIdx.x;
  for (int e = t; e < Nv; e += 256) {
    float x = p[(b * Nv + e) * 3 + 0];
    float y = p[(b * Nv + e) * 3 + 1];
    float z = p[(b * Nv + e) * 3 + 2];
    float s = ((x * x) + (y * y)) + (z * z);
    pnts[e] = make_float4(x, y, z, s);
  }
  __syncthreads();
  {
    const int ql = t >> 2, r = t & 3;
    const float4 q = pnts[q0 + ql];
    float bd[NSv]; int bi[NSv];
#pragma unroll
    for (int i = 0; i < NSv; i++) { bd[i] = 1e30f; bi[i] = 0; }
    const int m0 = r * 128;
#pragma unroll 1
    for (int i = 0; i < 128; i++) {
      const int m = m0 + i;
      const float4 c = pnts[m];
      float dot = __builtin_fmaf(q.z, c.z, __builtin_fmaf(q.y, c.y, q.x * c.x));
      float d = (q.w + c.w) - (2.0f * dot);
      bool cm[NSv];
#pragma unroll
      for (int j = 0; j < NSv; j++) cm[j] = bd[j] > d;
#pragma unroll
      for (int j = NSv - 1; j > 0; j--) {
        bd[j] = cm[j - 1] ? bd[j - 1] : (cm[j] ? d : bd[j]);
        bi[j] = cm[j - 1] ? bi[j - 1] : (cm[j] ? m : bi[j]);
      }
      bd[0] = cm[0] ? d : bd[0];
      bi[0] = cm[0] ? m : bi[0];
    }
#pragma unroll
    for (int j = 0; j < NSv; j++) { ld[ql][r * 16 + j] = bd[j]; li[ql][r * 16 + j] = bi[j]; }
  }
  __syncthreads();
  if (t < 64) {
    float bd[NSv]; int bi[NSv];
#pragma unroll
    for (int i = 0; i < NSv; i++) { bd[i] = 1e30f; bi[i] = 0; }
#pragma unroll 1
    for (int e = 0; e < 64; e++) {
      float d = ld[t][e];
      int   m = li[t][e];
      bool cm[NSv];
#pragma unroll
      for (int j = 0; j < NSv; j++) cm[j] = bd[j] > d;
#pragma unroll
      for (int j = NSv - 1; j > 0; j--) {
        bd[j] = cm[j - 1] ? bd[j - 1] : (cm[j] ? d : bd[j]);
        bi[j] = cm[j - 1] ? bi[j - 1] : (cm[j] ? m : bi[j]);
      }
      bd[0] = cm[0] ? d : bd[0];
      bi[0] = cm[0] ? m : bi[0];
    }
    int* o = idx_out + (b * Nv + q0 + t) * NSv;
#pragma unroll
    for (int j = 0; j < NSv; j++) o[j] = bi[j];
  }
}

// ---------------- QKV via bf16 MFMA (unchanged from round 11, PASS) ----------------
#define ASTR 20

__global__ __launch_bounds__(256) void qkv_mfma(
    const float* __restrict__ x,
    const float* __restrict__ Wq, const float* __restrict__ bq,
    const float* __restrict__ Wk, const float* __restrict__ bk,
    const float* __restrict__ Wv, const float* __restrict__ bv,
    float* __restrict__ xq, float* __restrict__ xk, float* __restrict__ xv) {
  __shared__ u32 As[128 * ASTR];
  __shared__ u32 Ws[3 * 64 * ASTR];
  const int mt  = blockIdx.x;
  const int b   = mt >> 2;
  const int m0c = (mt & 3) * 128;
  const int j0  = blockIdx.y * 64;
  const int t   = threadIdx.x;
  const int lane = t & 63, w = t >> 6;
  const int l15 = lane & 15, quad = lane >> 4;
  const float* xb = x + b * 512 * 512;

  f32x4 acc[4][3][2];
#pragma unroll
  for (int a1 = 0; a1 < 4; a1++)
#pragma unroll
    for (int a2 = 0; a2 < 3; a2++)
#pragma unroll
      for (int a3 = 0; a3 < 2; a3++) acc[a1][a2][a3] = (f32x4){0.f, 0.f, 0.f, 0.f};

  for (int k0 = 0; k0 < 512; k0 += 32) {
    if (t < 128) {
      const int oct = t & 3, mg = t >> 2;
      const int m = mg * 4;
      const int kb = k0 + oct * 8;
      union { float4 v; float s[4]; } f[8];
#pragma unroll
      for (int kk = 0; kk < 8; kk++)
        f[kk].v = *(const float4*)&xb[(kb + kk) * 512 + m0c + m];
#pragma unroll
      for (int i = 0; i < 4; i++) {
        uint4 pk;
        pk.x = pack2(f[0].s[i], f[1].s[i]);
        pk.y = pack2(f[2].s[i], f[3].s[i]);
        pk.z = pack2(f[4].s[i], f[5].s[i]);
        pk.w = pack2(f[6].s[i], f[7].s[i]);
        *(uint4*)&As[(m + i) * ASTR + oct * 4] = pk;
      }
    }
    if (t < 192) {
      const int mat = t >> 6, rr = t & 63;
      const int oct = rr & 3, jg = rr >> 2;
      const int j = jg * 4;
      const int kb = k0 + oct * 8;
      const float* Wm = (mat == 0) ? Wq : (mat == 1) ? Wk : Wv;
      union { float4 v; float s[4]; } f[8];
#pragma unroll
      for (int kk = 0; kk < 8; kk++)
        f[kk].v = *(const float4*)&Wm[(kb + kk) * 512 + j0 + j];
#pragma unroll
      for (int i = 0; i < 4; i++) {
        uint4 pk;
        pk.x = pack2(f[0].s[i], f[1].s[i]);
        pk.y = pack2(f[2].s[i], f[3].s[i]);
        pk.z = pack2(f[4].s[i], f[5].s[i]);
        pk.w = pack2(f[6].s[i], f[7].s[i]);
        *(uint4*)&Ws[mat * 64 * ASTR + (j + i) * ASTR + oct * 4] = pk;
      }
    }
    __syncthreads();
    const bf16x8 a0 = *(const bf16x8*)&As[((2 * w + 0) * 16 + l15) * ASTR + quad * 4];
    const bf16x8 a1 = *(const bf16x8*)&As[((2 * w + 1) * 16 + l15) * ASTR + quad * 4];
#pragma unroll
    for (int js = 0; js < 4; js++)
#pragma unroll
      for (int mat = 0; mat < 3; mat++) {
        const bf16x8 bfr =
            *(const bf16x8*)&Ws[mat * 64 * ASTR + (js * 16 + l15) * ASTR + quad * 4];
        acc[js][mat][0] = __builtin_amdgcn_mfma_f32_16x16x32_bf16(a0, bfr, acc[js][mat][0], 0, 0, 0);
        acc[js][mat][1] = __builtin_amdgcn_mfma_f32_16x16x32_bf16(a1, bfr, acc[js][mat][1], 0, 0, 0);
      }
    __syncthreads();
  }

  float bias[4][3];
#pragma unroll
  for (int js = 0; js < 4; js++) {
    bias[js][0] = bq[j0 + js * 16 + l15];
    bias[js][1] = bk[j0 + js * 16 + l15];
    bias[js][2] = bv[j0 + js * 16 + l15];
  }
#pragma unroll
  for (int js = 0; js < 4; js++)
#pragma unroll
    for (int mat = 0; mat < 3; mat++) {
      float* op = (mat == 0) ? xq : (mat == 1) ? xk : xv;
#pragma unroll
      for (int st = 0; st < 2; st++) {
        const int base = (b * 512 + m0c + (2 * w + st) * 16 + quad * 4) * 512 +
                         j0 + js * 16 + l15;
        const f32x4 v = acc[js][mat][st];
#pragma unroll
        for (int reg = 0; reg < 4; reg++) op[base + reg * 512] = v[reg] + bias[js][mat];
      }
    }
}

// ---------------- fused attention v3: t1/t2 via bf16 MFMA ----------------
// ubf[128][36] u32: u (bf16 pairs, A-layout) -> r1 (as u16[128][72])
// wbf[64][36]  u32: w1 chunk -> w2 (B-layout)
// lg overlays the arena after t2: [128][66] fp32 logits -> softmax weights
#define NQ  8
#define USTR 36
#define LSd 66

__global__ __launch_bounds__(256) void attn_kernel(
    const float* __restrict__ p, const int* __restrict__ idx,
    const float* __restrict__ xq, const float* __restrict__ xk, const float* __restrict__ xv,
    const float* __restrict__ p1W, const float* __restrict__ p1b,
    const float* __restrict__ pbg, const float* __restrict__ pbb,
    const float* __restrict__ p2W, const float* __restrict__ p2b,
    const float* __restrict__ bn1g, const float* __restrict__ bn1b,
    const float* __restrict__ w1W, const float* __restrict__ w1b,
    const float* __restrict__ bn2g, const float* __restrict__ bn2b,
    const float* __restrict__ w2W, const float* __restrict__ w2b,
    float* __restrict__ out) {
  const float rno = 1.0f / sqrtf(1.0f + 1e-5f);
  const int b  = blockIdx.y;
  const int n0 = blockIdx.x * NQ;
  const int t  = threadIdx.x;
  __shared__ float ARN[8448];          // 33792 B arena
  __shared__ float h_s[128][3];
  __shared__ int   idx_s[128];
  u32* ubf = (u32*)ARN;                // [0, 4608) u32
  u32* wbf = (u32*)ARN + 128 * USTR;   // [4608, 6912) u32

  if (t < 128) idx_s[t] = idx[(b * Nv + n0 + (t >> 4)) * NSv + (t & 15)] & (Nv - 1);
  __syncthreads();

  for (int e = t; e < 384; e += 256) {
    const int row = e / 3, j = e % 3;
    const int m = idx_s[row];
    const int n = n0 + (row >> 4);
    float d0 = p[(b * Nv + m) * 3 + 0] - p[(b * Nv + n) * 3 + 0];
    float d1 = p[(b * Nv + m) * 3 + 1] - p[(b * Nv + n) * 3 + 1];
    float d2 = p[(b * Nv + m) * 3 + 2] - p[(b * Nv + n) * 3 + 2];
    float y = d0 * p1W[0 * 3 + j] + d1 * p1W[1 * 3 + j] + d2 * p1W[2 * 3 + j] + p1b[j];
    y = y * (pbg[j] * rno) + pbb[j];
    h_s[row][j] = fmaxf(y, 0.0f);
  }
  __syncthreads();

  const int lane = t & 63, w = t >> 6;
  const int l15 = lane & 15, quad = lane >> 4;

  f32x4 acc[2][4];
#pragma unroll
  for (int a1 = 0; a1 < 2; a1++)
#pragma unroll
    for (int a2 = 0; a2 < 4; a2++) acc[a1][a2] = (f32x4){0.f, 0.f, 0.f, 0.f};

  // ---- t1 = u(128x512) @ w1(512x64) via MFMA, K-chunks of 64 ----
  for (int kc = 0; kc < Cv; kc += 64) {
    {  // stage w1 chunk bf16, B-layout: wbf[j][k-pair]
      const int j = t >> 2, ks2 = (t & 3) * 16;
      const float* src = w1W + (kc + ks2) * 64 + j;
      u32* dstw = &wbf[j * USTR + ks2 / 2];
#pragma unroll
      for (int i = 0; i < 8; i++)
        dstw[i] = pack2(src[(2 * i) * 64], src[(2 * i + 1) * 64]);
    }
    {  // compute u chunk fp32 -> bf16 pairs, A-layout: ubf[row][k-pair]
      const int row = t >> 1, ci = (t & 1) * 32;
      const int m = idx_s[row];
      const float h0 = h_s[row][0], h1 = h_s[row][1], h2 = h_s[row][2];
      const float* xkr = xk + (b * Nv + m) * Cv + kc + ci;
      const float* xqr = xq + (b * Nv + n0 + (row >> 4)) * Cv + kc + ci;
      u32* dst = &ubf[row * USTR + (t & 1) * 16];
#pragma unroll
      for (int i2 = 0; i2 < 8; i2++) {
        const int c4 = kc + ci + i2 * 4;
        const float4 kv  = *(const float4*)&xkr[i2 * 4];
        const float4 qv  = *(const float4*)&xqr[i2 * 4];
        const float4 pa  = *(const float4*)&p2W[c4];
        const float4 pbv = *(const float4*)&p2W[512 + c4];
        const float4 pcv = *(const float4*)&p2W[1024 + c4];
        const float4 pdv = *(const float4*)&p2b[c4];
        const float4 g1  = *(const float4*)&bn1g[c4];
        const float4 b1  = *(const float4*)&bn1b[c4];
        float u0 = fmaxf((kv.x - qv.x + h0 * pa.x + h1 * pbv.x + h2 * pcv.x + pdv.x) * (g1.x * rno) + b1.x, 0.f);
        float u1 = fmaxf((kv.y - qv.y + h0 * pa.y + h1 * pbv.y + h2 * pcv.y + pdv.y) * (g1.y * rno) + b1.y, 0.f);
        float u2 = fmaxf((kv.z - qv.z + h0 * pa.z + h1 * pbv.z + h2 * pcv.z + pdv.z) * (g1.z * rno) + b1.z, 0.f);
        float u3 = fmaxf((kv.w - qv.w + h0 * pa.w + h1 * pbv.w + h2 * pcv.w + pdv.w) * (g1.w * rno) + b1.w, 0.f);
        dst[i2 * 2]     = pack2(u0, u1);
        dst[i2 * 2 + 1] = pack2(u2, u3);
      }
    }
    __syncthreads();
#pragma unroll
    for (int ks = 0; ks < 2; ks++) {
      const bf16x8 a0 = *(const bf16x8*)&ubf[((2 * w + 0) * 16 + l15) * USTR + ks * 16 + quad * 4];
      const bf16x8 a1 = *(const bf16x8*)&ubf[((2 * w + 1) * 16 + l15) * USTR + ks * 16 + quad * 4];
#pragma unroll
      for (int js = 0; js < 4; js++) {
        const bf16x8 bfr = *(const bf16x8*)&wbf[(js * 16 + l15) * USTR + ks * 16 + quad * 4];
        acc[0][js] = __builtin_amdgcn_mfma_f32_16x16x32_bf16(a0, bfr, acc[0][js], 0, 0, 0);
        acc[1][js] = __builtin_amdgcn_mfma_f32_16x16x32_bf16(a1, bfr, acc[1][js], 0, 0, 0);
      }
    }
    __syncthreads();
  }

  // ---- r1 = relu(bn2(t1 + w1b)) -> bf16 A-layout; stage w2 ----
  {
    u16* r1h = (u16*)ubf;
#pragma unroll
    for (int js = 0; js < 4; js++) {
      const int j = js * 16 + l15;
      const float wb = w1b[j], s2 = bn2g[j] * rno, b2 = bn2b[j];
#pragma unroll
      for (int st = 0; st < 2; st++) {
        const int rbase = (2 * w + st) * 16 + quad * 4;
#pragma unroll
        for (int reg = 0; reg < 4; reg++) {
          float v = fmaxf((acc[st][js][reg] + wb) * s2 + b2, 0.f);
          r1h[(rbase + reg) * (USTR * 2) + j] = f2bf(v);
        }
      }
    }
  }
  {  // stage w2 bf16 B-layout
    const int j = t >> 2, ks2 = (t & 3) * 16;
    const float* src = w2W + ks2 * 64 + j;
    u32* dstw = &wbf[j * USTR + ks2 / 2];
#pragma unroll
    for (int i = 0; i < 8; i++)
      dstw[i] = pack2(src[(2 * i) * 64], src[(2 * i + 1) * 64]);
  }
  __syncthreads();

  // ---- t2 = r1(128x64) @ w2(64x64) via MFMA ----
  f32x4 acc2[2][4];
#pragma unroll
  for (int a1 = 0; a1 < 2; a1++)
#pragma unroll
    for (int a2 = 0; a2 < 4; a2++) acc2[a1][a2] = (f32x4){0.f, 0.f, 0.f, 0.f};
#pragma unroll
  for (int ks = 0; ks < 2; ks++) {
    const bf16x8 a0 = *(const bf16x8*)&ubf[((2 * w + 0) * 16 + l15) * USTR + ks * 16 + quad * 4];
    const bf16x8 a1 = *(const bf16x8*)&ubf[((2 * w + 1) * 16 + l15) * USTR + ks * 16 + quad * 4];
#pragma unroll
    for (int js = 0; js < 4; js++) {
      const bf16x8 bfr = *(const bf16x8*)&wbf[(js * 16 + l15) * USTR + ks * 16 + quad * 4];
      acc2[0][js] = __builtin_amdgcn_mfma_f32_16x16x32_bf16(a0, bfr, acc2[0][js], 0, 0, 0);
      acc2[1][js] = __builtin_amdgcn_mfma_f32_16x16x32_bf16(a1, bfr, acc2[1][js], 0, 0, 0);
    }
  }
  __syncthreads();   // all ubf/wbf reads done before lg overwrites the arena

  // ---- logits -> lg[row][j] (fp32, stride 66) ----
  {
    float* lg = ARN;
#pragma unroll
    for (int js = 0; js < 4; js++) {
      const float wb2 = w2b[js * 16 + l15];
#pragma unroll
      for (int st = 0; st < 2; st++) {
        const int rbase = (2 * w + st) * 16 + quad * 4;
#pragma unroll
        for (int reg = 0; reg < 4; reg++)
          lg[(rbase + reg) * LSd + js * 16 + l15] = acc2[st][js][reg] + wb2;
      }
    }
  }
  __syncthreads();

  // ---- softmax over the 16 neighbors, per (q, jj) ----
#pragma unroll
  for (int pp = 0; pp < 2; pp++) {
    const int pair = t + pp * 256;
    const int q = pair >> 6, jj = pair & 63;
    float* base = &ARN[(q * 16) * LSd + jj];
    float v[NSv];
#pragma unroll
    for (int k = 0; k < NSv; k++) v[k] = base[k * LSd];
    float mx = v[0];
#pragma unroll
    for (int k = 1; k < NSv; k++) mx = fmaxf(mx, v[k]);
    float s = 0.0f;
#pragma unroll
    for (int k = 0; k < NSv; k++) { v[k] = expf(v[k] - mx); s += v[k]; }
    const float is = 1.0f / s;
#pragma unroll
    for (int k = 0; k < NSv; k++) base[k * LSd] = v[k] * is;
  }
  __syncthreads();

  // ---- out[q][c] = sum_k (xv_g + pr) * sm[q*16+k][c&63] ----
  {
    const int q = t >> 5, cb = t & 31;
    float hk0[NSv], hk1[NSv], hk2[NSv];
    int mk[NSv];
#pragma unroll
    for (int k = 0; k < NSv; k++) {
      hk0[k] = h_s[q * 16 + k][0];
      hk1[k] = h_s[q * 16 + k][1];
      hk2[k] = h_s[q * 16 + k][2];
      mk[k]  = idx_s[q * 16 + k];
    }
    const float* smb = &ARN[(q * 16) * LSd];
    float* ob = out + (b * Nv + n0 + q) * Cv;
#pragma unroll 1
    for (int i = 0; i < 16; i++) {
      const int c = cb + i * 32;
      const float pa = p2W[c], pb2 = p2W[512 + c], pc = p2W[1024 + c], pd = p2b[c];
      const int jj = c & 63;
      float acco = 0.0f;
#pragma unroll
      for (int k = 0; k < NSv; k++) {
        float pr = hk0[k] * pa + hk1[k] * pb2 + hk2[k] * pc + pd;
        float val = xv[(b * Nv + mk[k]) * Cv + c] + pr;
        acco = fmaf(val, smb[k * LSd + jj], acco);
      }
      ob[c] = acco;
    }
  }
}

extern "C" void kernel_launch(void* const* d_in, const int* in_sizes, int n_in,
                              void* d_out, int out_size, void* d_ws, size_t ws_size,
                              hipStream_t stream) {
  const float* p    = (const float*)d_in[0];
  const float* x    = (const float*)d_in[1];
  const float* Wq   = (const float*)d_in[2];
  const float* bq   = (const float*)d_in[3];
  const float* Wk   = (const float*)d_in[4];
  const float* bk   = (const float*)d_in[5];
  const float* Wv   = (const float*)d_in[6];
  const float* bv   = (const float*)d_in[7];
  const float* p1W  = (const float*)d_in[8];
  const float* p1b  = (const float*)d_in[9];
  const float* pbg  = (const float*)d_in[10];
  const float* pbb  = (const float*)d_in[11];
  const float* p2W  = (const float*)d_in[12];
  const float* p2b  = (const float*)d_in[13];
  const float* bn1g = (const float*)d_in[14];
  const float* bn1b = (const float*)d_in[15];
  const float* w1W  = (const float*)d_in[16];
  const float* w1b  = (const float*)d_in[17];
  const float* bn2g = (const float*)d_in[18];
  const float* bn2b = (const float*)d_in[19];
  const float* w2W  = (const float*)d_in[20];
  const float* w2b  = (const float*)d_in[21];

  // ws layout (bytes): idx int [0, 524288) | xq/xk/xv fp32, 16 MiB each -> total ~48.5 MiB
  int*   idxb = (int*)d_ws;
  float* xq   = (float*)((char*)d_ws + 524288);
  float* xk   = xq + 8192 * 512;
  float* xv   = xk + 8192 * 512;

  knn_kernel<<<dim3(8, 16), 256, 0, stream>>>(p, idxb);
  qkv_mfma<<<dim3(64, 8), 256, 0, stream>>>(x, Wq, bq, Wk, bk, Wv, bv, xq, xk, xv);
  attn_kernel<<<dim3(Nv / NQ, Bv), 256, 0, stream>>>(p, idxb, xq, xk, xv,
                                                     p1W, p1b, pbg, pbb, p2W, p2b,
                                                     bn1g, bn1b, w1W, w1b, bn2g, bn2b,
                                                     w2W, w2b, (float*)d_out);
}

// Round 13
// 294.444 us; speedup vs baseline: 1.4658x; 1.4658x over previous
//
#include <hip/hip_runtime.h>

typedef unsigned short u16;
typedef unsigned int   u32;

#define Bv  16
#define Nv  512
#define Cv  512
#define NSv 16
#define CCv 64

typedef __attribute__((ext_vector_type(8))) short bf16x8;
typedef __attribute__((ext_vector_type(4))) float f32x4;

__device__ __forceinline__ u16 f2bf(float f) {   // RNE fp32 -> bf16
  u32 b = __float_as_uint(f);
  return (u16)((b + 0x7fffu + ((b >> 16) & 1u)) >> 16);
}
__device__ __forceinline__ u32 pack2(float lo, float hi) {
  return (u32)f2bf(lo) | ((u32)f2bf(hi) << 16);
}

// ---------------- kNN: register-resident compare-exchange top-16 (unchanged, PASS) ----------
__global__ __launch_bounds__(256) void knn_kernel(const float* __restrict__ p,
                                                  int* __restrict__ idx_out) {
#pragma clang fp contract(off)
  __shared__ float4 pnts[Nv];
  __shared__ float  ld[64][65];
  __shared__ int    li[64][65];
  const int b  = blockIdx.y;
  const int q0 = blockIdx.x * 64;
  const int t  = threadIdx.x;
  for (int e = t; e < Nv; e += 256) {
    float x = p[(b * Nv + e) * 3 + 0];
    float y = p[(b * Nv + e) * 3 + 1];
    float z = p[(b * Nv + e) * 3 + 2];
    float s = ((x * x) + (y * y)) + (z * z);
    pnts[e] = make_float4(x, y, z, s);
  }
  __syncthreads();
  {
    const int ql = t >> 2, r = t & 3;
    const float4 q = pnts[q0 + ql];
    float bd[NSv]; int bi[NSv];
#pragma unroll
    for (int i = 0; i < NSv; i++) { bd[i] = 1e30f; bi[i] = 0; }
    const int m0 = r * 128;
#pragma unroll 1
    for (int i = 0; i < 128; i++) {
      const int m = m0 + i;
      const float4 c = pnts[m];
      float dot = __builtin_fmaf(q.z, c.z, __builtin_fmaf(q.y, c.y, q.x * c.x));
      float d = (q.w + c.w) - (2.0f * dot);
      bool cm[NSv];
#pragma unroll
      for (int j = 0; j < NSv; j++) cm[j] = bd[j] > d;
#pragma unroll
      for (int j = NSv - 1; j > 0; j--) {
        bd[j] = cm[j - 1] ? bd[j - 1] : (cm[j] ? d : bd[j]);
        bi[j] = cm[j - 1] ? bi[j - 1] : (cm[j] ? m : bi[j]);
      }
      bd[0] = cm[0] ? d : bd[0];
      bi[0] = cm[0] ? m : bi[0];
    }
#pragma unroll
    for (int j = 0; j < NSv; j++) { ld[ql][r * 16 + j] = bd[j]; li[ql][r * 16 + j] = bi[j]; }
  }
  __syncthreads();
  if (t < 64) {
    float bd[NSv]; int bi[NSv];
#pragma unroll
    for (int i = 0; i < NSv; i++) { bd[i] = 1e30f; bi[i] = 0; }
#pragma unroll 1
    for (int e = 0; e < 64; e++) {
      float d = ld[t][e];
      int   m = li[t][e];
      bool cm[NSv];
#pragma unroll
      for (int j = 0; j < NSv; j++) cm[j] = bd[j] > d;
#pragma unroll
      for (int j = NSv - 1; j > 0; j--) {
        bd[j] = cm[j - 1] ? bd[j - 1] : (cm[j] ? d : bd[j]);
        bi[j] = cm[j - 1] ? bi[j - 1] : (cm[j] ? m : bi[j]);
      }
      bd[0] = cm[0] ? d : bd[0];
      bi[0] = cm[0] ? m : bi[0];
    }
    int* o = idx_out + (b * Nv + q0 + t) * NSv;
#pragma unroll
    for (int j = 0; j < NSv; j++) o[j] = bi[j];
  }
}

// ---------------- QKV via bf16 MFMA (unchanged from round 11, PASS) ----------------
#define ASTR 20

__global__ __launch_bounds__(256) void qkv_mfma(
    const float* __restrict__ x,
    const float* __restrict__ Wq, const float* __restrict__ bq,
    const float* __restrict__ Wk, const float* __restrict__ bk,
    const float* __restrict__ Wv, const float* __restrict__ bv,
    float* __restrict__ xq, float* __restrict__ xk, float* __restrict__ xv) {
  __shared__ u32 As[128 * ASTR];
  __shared__ u32 Ws[3 * 64 * ASTR];
  const int mt  = blockIdx.x;
  const int b   = mt >> 2;
  const int m0c = (mt & 3) * 128;
  const int j0  = blockIdx.y * 64;
  const int t   = threadIdx.x;
  const int lane = t & 63, w = t >> 6;
  const int l15 = lane & 15, quad = lane >> 4;
  const float* xb = x + b * 512 * 512;

  f32x4 acc[4][3][2];
#pragma unroll
  for (int a1 = 0; a1 < 4; a1++)
#pragma unroll
    for (int a2 = 0; a2 < 3; a2++)
#pragma unroll
      for (int a3 = 0; a3 < 2; a3++) acc[a1][a2][a3] = (f32x4){0.f, 0.f, 0.f, 0.f};

  for (int k0 = 0; k0 < 512; k0 += 32) {
    if (t < 128) {
      const int oct = t & 3, mg = t >> 2;
      const int m = mg * 4;
      const int kb = k0 + oct * 8;
      union { float4 v; float s[4]; } f[8];
#pragma unroll
      for (int kk = 0; kk < 8; kk++)
        f[kk].v = *(const float4*)&xb[(kb + kk) * 512 + m0c + m];
#pragma unroll
      for (int i = 0; i < 4; i++) {
        uint4 pk;
        pk.x = pack2(f[0].s[i], f[1].s[i]);
        pk.y = pack2(f[2].s[i], f[3].s[i]);
        pk.z = pack2(f[4].s[i], f[5].s[i]);
        pk.w = pack2(f[6].s[i], f[7].s[i]);
        *(uint4*)&As[(m + i) * ASTR + oct * 4] = pk;
      }
    }
    if (t < 192) {
      const int mat = t >> 6, rr = t & 63;
      const int oct = rr & 3, jg = rr >> 2;
      const int j = jg * 4;
      const int kb = k0 + oct * 8;
      const float* Wm = (mat == 0) ? Wq : (mat == 1) ? Wk : Wv;
      union { float4 v; float s[4]; } f[8];
#pragma unroll
      for (int kk = 0; kk < 8; kk++)
        f[kk].v = *(const float4*)&Wm[(kb + kk) * 512 + j0 + j];
#pragma unroll
      for (int i = 0; i < 4; i++) {
        uint4 pk;
        pk.x = pack2(f[0].s[i], f[1].s[i]);
        pk.y = pack2(f[2].s[i], f[3].s[i]);
        pk.z = pack2(f[4].s[i], f[5].s[i]);
        pk.w = pack2(f[6].s[i], f[7].s[i]);
        *(uint4*)&Ws[mat * 64 * ASTR + (j + i) * ASTR + oct * 4] = pk;
      }
    }
    __syncthreads();
    const bf16x8 a0 = *(const bf16x8*)&As[((2 * w + 0) * 16 + l15) * ASTR + quad * 4];
    const bf16x8 a1 = *(const bf16x8*)&As[((2 * w + 1) * 16 + l15) * ASTR + quad * 4];
#pragma unroll
    for (int js = 0; js < 4; js++)
#pragma unroll
      for (int mat = 0; mat < 3; mat++) {
        const bf16x8 bfr =
            *(const bf16x8*)&Ws[mat * 64 * ASTR + (js * 16 + l15) * ASTR + quad * 4];
        acc[js][mat][0] = __builtin_amdgcn_mfma_f32_16x16x32_bf16(a0, bfr, acc[js][mat][0], 0, 0, 0);
        acc[js][mat][1] = __builtin_amdgcn_mfma_f32_16x16x32_bf16(a1, bfr, acc[js][mat][1], 0, 0, 0);
      }
    __syncthreads();
  }

  float bias[4][3];
#pragma unroll
  for (int js = 0; js < 4; js++) {
    bias[js][0] = bq[j0 + js * 16 + l15];
    bias[js][1] = bk[j0 + js * 16 + l15];
    bias[js][2] = bv[j0 + js * 16 + l15];
  }
#pragma unroll
  for (int js = 0; js < 4; js++)
#pragma unroll
    for (int mat = 0; mat < 3; mat++) {
      float* op = (mat == 0) ? xq : (mat == 1) ? xk : xv;
#pragma unroll
      for (int st = 0; st < 2; st++) {
        const int base = (b * 512 + m0c + (2 * w + st) * 16 + quad * 4) * 512 +
                         j0 + js * 16 + l15;
        const f32x4 v = acc[js][mat][st];
#pragma unroll
        for (int reg = 0; reg < 4; reg++) op[base + reg * 512] = v[reg] + bias[js][mat];
      }
    }
}

// ---------------- fused attention v4: coefficient LDS tables + pipelined gather ----------
// Arena ARN[13056] floats (52224 B):
//   Sf[512] A0[512] A1[512] A2[512] Qm[8*512]   [0, 6144)      (t1 only)
//   wbf = u32[64*36]                            [6144, 8448)   (t1/t2)
//   ubf = u32[128*36]                           [8448, 13056)  (t1/t2; r1 between)
//   lg  = float[128*66] overlays [0, 8448)      (post-t2)
#define NQ  8
#define USTR 36
#define LSd 66

__global__ __launch_bounds__(256) void attn_kernel(
    const float* __restrict__ p, const int* __restrict__ idx,
    const float* __restrict__ xq, const float* __restrict__ xk, const float* __restrict__ xv,
    const float* __restrict__ p1W, const float* __restrict__ p1b,
    const float* __restrict__ pbg, const float* __restrict__ pbb,
    const float* __restrict__ p2W, const float* __restrict__ p2b,
    const float* __restrict__ bn1g, const float* __restrict__ bn1b,
    const float* __restrict__ w1W, const float* __restrict__ w1b,
    const float* __restrict__ bn2g, const float* __restrict__ bn2b,
    const float* __restrict__ w2W, const float* __restrict__ w2b,
    float* __restrict__ out) {
  const float rno = 1.0f / sqrtf(1.0f + 1e-5f);
  const int b  = blockIdx.y;
  const int n0 = blockIdx.x * NQ;
  const int t  = threadIdx.x;
  __shared__ float ARN[13056];
  __shared__ float h_s[128][3];
  __shared__ int   idx_s[128];
  float* Sf  = ARN;
  float* A0f = ARN + 512;
  float* A1f = ARN + 1024;
  float* A2f = ARN + 1536;
  float* Qmf = ARN + 2048;
  u32* wbf = (u32*)(ARN + 6144);
  u32* ubf = (u32*)(ARN + 8448);

  if (t < 128) idx_s[t] = idx[(b * Nv + n0 + (t >> 4)) * NSv + (t & 15)] & (Nv - 1);

  // folded coefficient tables: S = s1, A* = p2W_row * s1
  {
    const int c0 = t * 2;
#pragma unroll
    for (int i = 0; i < 2; i++) {
      const int c = c0 + i;
      const float s1 = bn1g[c] * rno;
      Sf[c]  = s1;
      A0f[c] = p2W[c] * s1;
      A1f[c] = p2W[512 + c] * s1;
      A2f[c] = p2W[1024 + c] * s1;
    }
  }
  // Qm[q][c] = (p2b[c] - xq[q][c]) * s1 + b1[c]   (absorbs the xq gather)
  {
    const int q = t >> 5, cq0 = (t & 31) * 16;
    const float* xqr = xq + (b * Nv + n0 + q) * Cv + cq0;
#pragma unroll
    for (int i = 0; i < 4; i++) {
      const int c = cq0 + i * 4;
      const float4 xq4 = *(const float4*)&xqr[i * 4];
      const float4 pd4 = *(const float4*)&p2b[c];
      const float4 g4  = *(const float4*)&bn1g[c];
      const float4 b4  = *(const float4*)&bn1b[c];
      float4 r;
      r.x = (pd4.x - xq4.x) * (g4.x * rno) + b4.x;
      r.y = (pd4.y - xq4.y) * (g4.y * rno) + b4.y;
      r.z = (pd4.z - xq4.z) * (g4.z * rno) + b4.z;
      r.w = (pd4.w - xq4.w) * (g4.w * rno) + b4.w;
      *(float4*)&Qmf[q * 512 + c] = r;
    }
  }
  __syncthreads();

  for (int e = t; e < 384; e += 256) {
    const int row = e / 3, j = e % 3;
    const int m = idx_s[row];
    const int n = n0 + (row >> 4);
    float d0 = p[(b * Nv + m) * 3 + 0] - p[(b * Nv + n) * 3 + 0];
    float d1 = p[(b * Nv + m) * 3 + 1] - p[(b * Nv + n) * 3 + 1];
    float d2 = p[(b * Nv + m) * 3 + 2] - p[(b * Nv + n) * 3 + 2];
    float y = d0 * p1W[0 * 3 + j] + d1 * p1W[1 * 3 + j] + d2 * p1W[2 * 3 + j] + p1b[j];
    y = y * (pbg[j] * rno) + pbb[j];
    h_s[row][j] = fmaxf(y, 0.0f);
  }

  // xk chunk-0 prefetch (idx_s valid after first barrier)
  const int row = t >> 1, ci = (t & 1) * 32;
  const int mrow = idx_s[row];
  const float* xkr = xk + (b * Nv + mrow) * Cv + ci;
  const float* qmr = Qmf + (row >> 4) * 512 + ci;
  float4 pf[8];
#pragma unroll
  for (int i = 0; i < 8; i++) pf[i] = *(const float4*)&xkr[i * 4];
  __syncthreads();

  const int lane = t & 63, w = t >> 6;
  const int l15 = lane & 15, quad = lane >> 4;
  const int jW = t >> 2, ks2W = (t & 3) * 16;
  const float h0 = h_s[row][0], h1 = h_s[row][1], h2 = h_s[row][2];

  f32x4 acc[2][4];
#pragma unroll
  for (int a1 = 0; a1 < 2; a1++)
#pragma unroll
    for (int a2 = 0; a2 < 4; a2++) acc[a1][a2] = (f32x4){0.f, 0.f, 0.f, 0.f};

  // ---- t1 = u(128x512) @ w1(512x64) via MFMA, pipelined K-chunks of 64 ----
  for (int kc = 0; kc < Cv; kc += 64) {
    // issue w1 loads early (consumed after the VALU-heavy u-compute)
    float wv[16];
    const float* srcW = w1W + (kc + ks2W) * 64 + jW;
#pragma unroll
    for (int i = 0; i < 16; i++) wv[i] = srcW[i * 64];
    // u = fma(xk,S, fma(h0,A0, fma(h1,A1, fma(h2,A2, Qm)))), relu, pack bf16
    {
      u32* dst = &ubf[row * USTR + (t & 1) * 16];
#pragma unroll
      for (int i2 = 0; i2 < 8; i2++) {
        const int c4 = kc + ci + i2 * 4;
        const float4 S4 = *(const float4*)&Sf[c4];
        const float4 a0 = *(const float4*)&A0f[c4];
        const float4 a1 = *(const float4*)&A1f[c4];
        const float4 a2 = *(const float4*)&A2f[c4];
        const float4 qm = *(const float4*)&qmr[kc + i2 * 4];
        float u0 = fmaxf(fmaf(pf[i2].x, S4.x, fmaf(h0, a0.x, fmaf(h1, a1.x, fmaf(h2, a2.x, qm.x)))), 0.f);
        float u1 = fmaxf(fmaf(pf[i2].y, S4.y, fmaf(h0, a0.y, fmaf(h1, a1.y, fmaf(h2, a2.y, qm.y)))), 0.f);
        float u2 = fmaxf(fmaf(pf[i2].z, S4.z, fmaf(h0, a0.z, fmaf(h1, a1.z, fmaf(h2, a2.z, qm.z)))), 0.f);
        float u3 = fmaxf(fmaf(pf[i2].w, S4.w, fmaf(h0, a0.w, fmaf(h1, a1.w, fmaf(h2, a2.w, qm.w)))), 0.f);
        dst[i2 * 2]     = pack2(u0, u1);
        dst[i2 * 2 + 1] = pack2(u2, u3);
      }
    }
    // prefetch next xk chunk (in flight across barrier + MFMA)
    if (kc + 64 < Cv) {
#pragma unroll
      for (int i = 0; i < 8; i++) pf[i] = *(const float4*)&xkr[kc + 64 + i * 4];
    }
    // pack + write w1 chunk
    {
      u32* dstw = &wbf[jW * USTR + (ks2W >> 1)];
#pragma unroll
      for (int i = 0; i < 8; i++) dstw[i] = pack2(wv[2 * i], wv[2 * i + 1]);
    }
    __syncthreads();
#pragma unroll
    for (int ks = 0; ks < 2; ks++) {
      const bf16x8 a0 = *(const bf16x8*)&ubf[((2 * w + 0) * 16 + l15) * USTR + ks * 16 + quad * 4];
      const bf16x8 a1 = *(const bf16x8*)&ubf[((2 * w + 1) * 16 + l15) * USTR + ks * 16 + quad * 4];
#pragma unroll
      for (int js = 0; js < 4; js++) {
        const bf16x8 bfr = *(const bf16x8*)&wbf[(js * 16 + l15) * USTR + ks * 16 + quad * 4];
        acc[0][js] = __builtin_amdgcn_mfma_f32_16x16x32_bf16(a0, bfr, acc[0][js], 0, 0, 0);
        acc[1][js] = __builtin_amdgcn_mfma_f32_16x16x32_bf16(a1, bfr, acc[1][js], 0, 0, 0);
      }
    }
    __syncthreads();
  }

  // ---- r1 = relu(bn2(t1 + w1b)) -> bf16 A-layout; stage w2 ----
  {
    u16* r1h = (u16*)ubf;
#pragma unroll
    for (int js = 0; js < 4; js++) {
      const int j = js * 16 + l15;
      const float wb = w1b[j], s2 = bn2g[j] * rno, b2 = bn2b[j];
#pragma unroll
      for (int st = 0; st < 2; st++) {
        const int rbase = (2 * w + st) * 16 + quad * 4;
#pragma unroll
        for (int reg = 0; reg < 4; reg++) {
          float v = fmaxf((acc[st][js][reg] + wb) * s2 + b2, 0.f);
          r1h[(rbase + reg) * (USTR * 2) + j] = f2bf(v);
        }
      }
    }
  }
  {
    const float* src = w2W + ks2W * 64 + jW;
    u32* dstw = &wbf[jW * USTR + (ks2W >> 1)];
#pragma unroll
    for (int i = 0; i < 8; i++)
      dstw[i] = pack2(src[(2 * i) * 64], src[(2 * i + 1) * 64]);
  }
  __syncthreads();

  // ---- t2 = r1(128x64) @ w2(64x64) via MFMA ----
  f32x4 acc2[2][4];
#pragma unroll
  for (int a1 = 0; a1 < 2; a1++)
#pragma unroll
    for (int a2 = 0; a2 < 4; a2++) acc2[a1][a2] = (f32x4){0.f, 0.f, 0.f, 0.f};
#pragma unroll
  for (int ks = 0; ks < 2; ks++) {
    const bf16x8 a0 = *(const bf16x8*)&ubf[((2 * w + 0) * 16 + l15) * USTR + ks * 16 + quad * 4];
    const bf16x8 a1 = *(const bf16x8*)&ubf[((2 * w + 1) * 16 + l15) * USTR + ks * 16 + quad * 4];
#pragma unroll
    for (int js = 0; js < 4; js++) {
      const bf16x8 bfr = *(const bf16x8*)&wbf[(js * 16 + l15) * USTR + ks * 16 + quad * 4];
      acc2[0][js] = __builtin_amdgcn_mfma_f32_16x16x32_bf16(a0, bfr, acc2[0][js], 0, 0, 0);
      acc2[1][js] = __builtin_amdgcn_mfma_f32_16x16x32_bf16(a1, bfr, acc2[1][js], 0, 0, 0);
    }
  }
  __syncthreads();   // coeff tables / wbf dead past here; lg overlays them

  // ---- logits -> lg[row][j] (fp32, stride 66) ----
  {
    float* lg = ARN;
#pragma unroll
    for (int js = 0; js < 4; js++) {
      const float wb2 = w2b[js * 16 + l15];
#pragma unroll
      for (int st = 0; st < 2; st++) {
        const int rbase = (2 * w + st) * 16 + quad * 4;
#pragma unroll
        for (int reg = 0; reg < 4; reg++)
          lg[(rbase + reg) * LSd + js * 16 + l15] = acc2[st][js][reg] + wb2;
      }
    }
  }
  __syncthreads();

  // ---- softmax over the 16 neighbors, per (q, jj) ----
#pragma unroll
  for (int pp = 0; pp < 2; pp++) {
    const int pair = t + pp * 256;
    const int q = pair >> 6, jj = pair & 63;
    float* base = &ARN[(q * 16) * LSd + jj];
    float v[NSv];
#pragma unroll
    for (int k = 0; k < NSv; k++) v[k] = base[k * LSd];
    float mx = v[0];
#pragma unroll
    for (int k = 1; k < NSv; k++) mx = fmaxf(mx, v[k]);
    float s = 0.0f;
#pragma unroll
    for (int k = 0; k < NSv; k++) { v[k] = expf(v[k] - mx); s += v[k]; }
    const float is = 1.0f / s;
#pragma unroll
    for (int k = 0; k < NSv; k++) base[k * LSd] = v[k] * is;
  }
  __syncthreads();

  // ---- out[q][c] = sum_k (xv_g + pr) * sm[q*16+k][c&63] ----
  {
    const int q = t >> 5, cb = t & 31;
    float hk0[NSv], hk1[NSv], hk2[NSv];
    int mk[NSv];
#pragma unroll
    for (int k = 0; k < NSv; k++) {
      hk0[k] = h_s[q * 16 + k][0];
      hk1[k] = h_s[q * 16 + k][1];
      hk2[k] = h_s[q * 16 + k][2];
      mk[k]  = idx_s[q * 16 + k];
    }
    const float* smb = &ARN[(q * 16) * LSd];
    float* ob = out + (b * Nv + n0 + q) * Cv;
#pragma unroll 1
    for (int i = 0; i < 16; i++) {
      const int c = cb + i * 32;
      const float pa = p2W[c], pb2 = p2W[512 + c], pc = p2W[1024 + c], pd = p2b[c];
      const int jj = c & 63;
      float acco = 0.0f;
#pragma unroll
      for (int k = 0; k < NSv; k++) {
        float pr = hk0[k] * pa + hk1[k] * pb2 + hk2[k] * pc + pd;
        float val = xv[(b * Nv + mk[k]) * Cv + c] + pr;
        acco = fmaf(val, smb[k * LSd + jj], acco);
      }
      ob[c] = acco;
    }
  }
}

extern "C" void kernel_launch(void* const* d_in, const int* in_sizes, int n_in,
                              void* d_out, int out_size, void* d_ws, size_t ws_size,
                              hipStream_t stream) {
  const float* p    = (const float*)d_in[0];
  const float* x    = (const float*)d_in[1];
  const float* Wq   = (const float*)d_in[2];
  const float* bq   = (const float*)d_in[3];
  const float* Wk   = (const float*)d_in[4];
  const float* bk   = (const float*)d_in[5];
  const float* Wv   = (const float*)d_in[6];
  const float* bv   = (const float*)d_in[7];
  const float* p1W  = (const float*)d_in[8];
  const float* p1b  = (const float*)d_in[9];
  const float* pbg  = (const float*)d_in[10];
  const float* pbb  = (const float*)d_in[11];
  const float* p2W  = (const float*)d_in[12];
  const float* p2b  = (const float*)d_in[13];
  const float* bn1g = (const float*)d_in[14];
  const float* bn1b = (const float*)d_in[15];
  const float* w1W  = (const float*)d_in[16];
  const float* w1b  = (const float*)d_in[17];
  const float* bn2g = (const float*)d_in[18];
  const float* bn2b = (const float*)d_in[19];
  const float* w2W  = (const float*)d_in[20];
  const float* w2b  = (const float*)d_in[21];

  // ws layout (bytes): idx int [0, 524288) | xq/xk/xv fp32, 16 MiB each -> total ~48.5 MiB
  int*   idxb = (int*)d_ws;
  float* xq   = (float*)((char*)d_ws + 524288);
  float* xk   = xq + 8192 * 512;
  float* xv   = xk + 8192 * 512;

  knn_kernel<<<dim3(8, 16), 256, 0, stream>>>(p, idxb);
  qkv_mfma<<<dim3(64, 8), 256, 0, stream>>>(x, Wq, bq, Wk, bk, Wv, bv, xq, xk, xv);
  attn_kernel<<<dim3(Nv / NQ, Bv), 256, 0, stream>>>(p, idxb, xq, xk, xv,
                                                     p1W, p1b, pbg, pbb, p2W, p2b,
                                                     bn1g, bn1b, w1W, w1b, bn2g, bn2b,
                                                     w2W, w2b, (float*)d_out);
}